// Round 1
// baseline (1302.926 us; speedup 1.0000x reference)
//
#include <hip/hip_runtime.h>
#include <math.h>

#define N_GRAPHS 512
#define N_PER    1024
#define NN       (N_GRAPHS * N_PER)   // 524288 nodes
#define NE       4194304              // edges
#define DF       256                  // feature dim
#define KK       512                  // keep per graph
#define GK       (N_GRAPHS * KK)      // 262144 output rows

// ---------------- init: acc=0 (double), deg=1.0f ----------------
__global__ void k_init(double* __restrict__ acc, float* __restrict__ deg) {
    int i = blockIdx.x * blockDim.x + threadIdx.x;
    if (i < NN) { acc[i] = 0.0; deg[i] = 1.0f; }
}

// ---------------- support = X @ W  (one wave per row) ----------------
__global__ void k_support(const float* __restrict__ X, const float* __restrict__ W,
                          float* __restrict__ support) {
    __shared__ float sW[DF];
    int t = threadIdx.x;          // 256 threads
    sW[t] = W[t];
    __syncthreads();
    int wv = t >> 6, lane = t & 63;
    int row = blockIdx.x * 4 + wv;              // grid = NN/4
    const float4 x = ((const float4*)(X + (size_t)row * DF))[lane];
    const float4 w = ((const float4*)sW)[lane];
    float s = x.x * w.x + x.y * w.y + x.z * w.z + x.w * w.w;
    #pragma unroll
    for (int off = 32; off; off >>= 1) s += __shfl_down(s, off, 64);
    if (lane == 0) support[row] = s;
}

// ---------------- edge scatter: acc[row] += adj*support[col]; deg count ----
__global__ void k_scatter(const int* __restrict__ row, const int* __restrict__ col,
                          const float* __restrict__ adj, const float* __restrict__ support,
                          double* __restrict__ acc, float* __restrict__ deg) {
    int e = blockIdx.x * blockDim.x + threadIdx.x;
    if (e >= NE) return;
    int r = row[e], c = col[e];
    float term = adj[e] * support[c];   // fp32 term like reference
    atomicAdd(&acc[r], (double)term);   // fp64 sum: order-independent to fp32 eps
    if (r != c) atomicAdd(&deg[r], 1.0f);
}

// ---------------- attn = tanh(acc); diag_norm = 1/deg ----------------
__global__ void k_finalize(const double* __restrict__ acc, const float* __restrict__ deg,
                           float* __restrict__ attn, float* __restrict__ diag) {
    int i = blockIdx.x * blockDim.x + threadIdx.x;
    if (i < NN) {
        attn[i] = tanhf((float)acc[i]);
        diag[i] = 1.0f / deg[i];
    }
}

// ---------------- per-graph top-k via full bitonic sort in LDS ----------------
// jax.lax.top_k order: descending value; ties -> smaller index first.
__global__ void k_topk(const float* __restrict__ attn, int* __restrict__ nidx) {
    __shared__ float sv[N_PER];
    __shared__ int   si[N_PER];
    int g = blockIdx.x, t = threadIdx.x;   // 1024 threads
    int base = g * N_PER;
    sv[t] = attn[base + t];
    si[t] = t;
    __syncthreads();
    for (int k = 2; k <= N_PER; k <<= 1) {
        for (int j = k >> 1; j > 0; j >>= 1) {
            int l = t ^ j;
            if (l > t) {
                float v1 = sv[t], v2 = sv[l];
                int   i1 = si[t], i2 = si[l];
                // cmp_l_t: element l should come before element t in final order
                bool cmp_l_t = (v2 > v1) || (v2 == v1 && i2 < i1);
                bool swap = ((t & k) == 0) ? cmp_l_t : !cmp_l_t;
                if (swap) { sv[t] = v2; si[t] = i2; sv[l] = v1; si[l] = i1; }
            }
            __syncthreads();
        }
    }
    if (t < KK) nidx[g * KK + t] = base + si[t];
}

// ---------------- hidden = X[node]*attn[node]; mask = graph_indicator[node] ---
__global__ void k_gather(const float* __restrict__ X, const float* __restrict__ attn,
                         const int* __restrict__ nidx, const int* __restrict__ gi,
                         float* __restrict__ hidden, float* __restrict__ mask) {
    int t = threadIdx.x;          // 256 threads
    int wv = t >> 6, lane = t & 63;
    int r = blockIdx.x * 4 + wv;                // grid = GK/4
    int node = nidx[r];
    float a = attn[node];
    float4 x = ((const float4*)(X + (size_t)node * DF))[lane];
    x.x *= a; x.y *= a; x.z *= a; x.w *= a;
    ((float4*)(hidden + (size_t)r * DF))[lane] = x;
    if (lane == 0) mask[r] = (float)gi[node];
}

// ---------------- edge_norm = nonself * rsqrt(deg[r]) * rsqrt(deg[c]) --------
__global__ void k_edgenorm(const int* __restrict__ row, const int* __restrict__ col,
                           const float* __restrict__ deg, float* __restrict__ en) {
    int e = blockIdx.x * blockDim.x + threadIdx.x;
    if (e >= NE) return;
    int r = row[e], c = col[e];
    float v = 0.0f;
    if (r != c) v = rsqrtf(deg[r]) * rsqrtf(deg[c]);
    en[e] = v;
}

extern "C" void kernel_launch(void* const* d_in, const int* in_sizes, int n_in,
                              void* d_out, int out_size, void* d_ws, size_t ws_size,
                              hipStream_t stream) {
    const int*   edge_index = (const int*)d_in[0];     // [2, NE]
    const float* adj_vals   = (const float*)d_in[1];   // [NE]
    const float* X          = (const float*)d_in[2];   // [NN, DF]
    const float* W          = (const float*)d_in[3];   // [DF]
    const int*   gi         = (const int*)d_in[4];     // [NN]

    const int* row = edge_index;
    const int* col = edge_index + NE;

    // outputs, concatenated flat fp32
    float* out_hidden = (float*)d_out;                       // GK*DF
    float* out_mask   = out_hidden + (size_t)GK * DF;        // GK
    float* out_edge   = out_mask + GK;                       // NE
    float* out_diag   = out_edge + NE;                       // NN

    // workspace layout
    char* ws = (char*)d_ws;
    float*  support = (float*)ws;                            // 2 MB
    double* acc     = (double*)(ws + (size_t)2  * 1024 * 1024); // 4 MB
    float*  deg     = (float*)(ws + (size_t)6  * 1024 * 1024);  // 2 MB
    float*  attn    = (float*)(ws + (size_t)8  * 1024 * 1024);  // 2 MB
    int*    nidx    = (int*)(ws + (size_t)10 * 1024 * 1024);    // 1 MB

    k_init<<<NN / 256, 256, 0, stream>>>(acc, deg);
    k_support<<<NN / 4, 256, 0, stream>>>(X, W, support);
    k_scatter<<<NE / 256, 256, 0, stream>>>(row, col, adj_vals, support, acc, deg);
    k_finalize<<<NN / 256, 256, 0, stream>>>(acc, deg, attn, out_diag);
    k_topk<<<N_GRAPHS, N_PER, 0, stream>>>(attn, nidx);
    k_gather<<<GK / 4, 256, 0, stream>>>(X, attn, nidx, gi, out_hidden, out_mask);
    k_edgenorm<<<NE / 256, 256, 0, stream>>>(row, col, deg, out_edge);
}